// Round 4
// baseline (301.445 us; speedup 1.0000x reference)
//
#include <hip/hip_runtime.h>
#include <hip/hip_bf16.h>

#define N_VOX 200000
#define CI 128
#define CO 128
#define KK 27
#define BM 128
#define NBLK 1563
#define NSTEP 54
#define LEAK 0.333f
#define BN_EPS 1e-4f

typedef unsigned short u16;
typedef unsigned int u32;
typedef __attribute__((ext_vector_type(8))) short short8;
typedef __attribute__((ext_vector_type(4))) float f32x4;

typedef const __attribute__((address_space(1))) u32* gptr_t;
typedef __attribute__((address_space(3))) u32* lptr_t;

__device__ __forceinline__ u16 f2bf(float f) {  // RNE
  union { float f; u32 u; } x; x.f = f;
  return (u16)((x.u + 0x7FFFu + ((x.u >> 16) & 1u)) >> 16);
}
__device__ __forceinline__ u16 cvt_bf(float f) {
  union { __hip_bfloat16 h; u16 u; } c;
  c.h = __float2bfloat16(f);
  return c.u;
}

// ---- feature cast f32 -> bf16 ----
__global__ __launch_bounds__(256) void fcast_kernel(const float* __restrict__ f,
                                                    u16* __restrict__ fb) {
  size_t i = ((size_t)blockIdx.x * 256 + threadIdx.x) * 8;
  float4 a = *(const float4*)(f + i);
  float4 b = *(const float4*)(f + i + 4);
  u16 t[8];
  t[0] = cvt_bf(a.x); t[1] = cvt_bf(a.y); t[2] = cvt_bf(a.z); t[3] = cvt_bf(a.w);
  t[4] = cvt_bf(b.x); t[5] = cvt_bf(b.y); t[6] = cvt_bf(b.z); t[7] = cvt_bf(b.w);
  *(uint4*)(fb + i) = *(const uint4*)t;
}

// ---- W repack for coalesced B-fragment loads:
// chunk = ((k*2+half)*2+ks)*8 + cb, lane (lr,lg):
// Wt2[chunk*512 + lane*8 + e] = bf16(W[k][half*64+ks*32+lg*8+e][cb*16+lr]) ----
__global__ __launch_bounds__(256) void wcast2_kernel(const float* __restrict__ W,
                                                     u16* __restrict__ Wt2) {
  int gid = blockIdx.x * 256 + threadIdx.x;  // 55296 total
  int lane = gid & 63, chunk = gid >> 6;
  int n8 = chunk & 7, ks = (chunk >> 3) & 1, half = (chunk >> 4) & 1, k = chunk >> 5;
  int lr = lane & 15, lg = lane >> 4;
  int co = n8 * 16 + lr;
  int ci0 = half * 64 + ks * 32 + lg * 8;
  const float* Wk = W + (size_t)k * CI * CO;
  u16 t[8];
#pragma unroll
  for (int e = 0; e < 8; ++e) t[e] = f2bf(Wk[(ci0 + e) * CO + co]);
  *(uint4*)(Wt2 + (size_t)gid * 8) = *(const uint4*)t;
}

// ---- fast conv: A glds ring-4 depth-3, B in regs from L2, counted vmcnt ----
__global__ __launch_bounds__(256, 2) void conv_kernel(
    const u16* __restrict__ featb, const u16* __restrict__ Wt2,
    const int* __restrict__ nb, const u16* __restrict__ zp,
    float* __restrict__ out, float* __restrict__ partial) {
  __shared__ __align__(16) char smem[79360];
  int* const nbs = (int*)(smem + 65536);    // 13824B
  float* const sq = (float*)smem;           // epilogue alias (post-barrier)

  const int tid = threadIdx.x;
  const int bid = blockIdx.x;
  const int row0 = bid * BM;

  for (int i = tid; i < BM * KK; i += 256) {
    int gi = row0 * KK + i;
    nbs[i] = (gi < N_VOX * KK) ? nb[gi] : -1;
  }
  __syncthreads();

  const int lane = tid & 63;
  const int wv = tid >> 6;
  const int wr = wv >> 1, wc = wv & 1;
  const int lr = lane & 15, lg = lane >> 4;

  f32x4 acc[4][4];
#pragma unroll
  for (int m = 0; m < 4; ++m)
#pragma unroll
    for (int n = 0; n < 4; ++n) acc[m][n] = (f32x4){0.f, 0.f, 0.f, 0.f};

  short8 b0[8], b1[8];

  // A gather into ring slot; source pre-swizzled so linear glds dst = XOR layout
  auto issueA = [&](int s, int slot) {
    if (s >= NSTEP) s = NSTEP - 1;  // clamped dummy (dead slot, uniform vmcnt)
    int k = s >> 1;
    int halfU = (s & 1) * 64;
    u16* Adst = (u16*)(smem + slot * 16384);
    int r = tid >> 3, cl = tid & 7;
#pragma unroll
    for (int j = 0; j < 4; ++j) {
      int row = j * 32 + r;
      int src = nbs[row * KK + k];
      const u16* g = (src >= 0) ? (featb + (size_t)src * CI + halfU) : zp;
      g += ((cl ^ (row & 7)) << 3);
      __builtin_amdgcn_global_load_lds((gptr_t)g, (lptr_t)(Adst + (j * 32 + wv * 8) * 64),
                                       16, 0, 0);
    }
  };

  // B fragments direct to regs; one coalesced 1KB burst per (n,ks)
  auto loadB = [&](int s, short8* bn) {
    if (s >= NSTEP) s = NSTEP - 1;
    int k = s >> 1, half = s & 1;
    const u16* base = Wt2 + (((k * 2 + half) * 16 + wc * 4) * 512) + lane * 8;
#pragma unroll
    for (int n = 0; n < 4; ++n)
#pragma unroll
      for (int ks = 0; ks < 2; ++ks)
        bn[n * 2 + ks] = *(const short8*)(base + (ks * 8 + n) * 512);
  };

  auto compute = [&](int slot, const short8* bc) {
    const char* A = smem + slot * 16384;
    __builtin_amdgcn_s_setprio(1);
#pragma unroll
    for (int ks = 0; ks < 2; ++ks) {
      short8 a[4];
#pragma unroll
      for (int m = 0; m < 4; ++m) {
        int r = wr * 64 + m * 16 + lr;
        a[m] = *(const short8*)(A + r * 128 + ((ks * 64 + lg * 16) ^ ((r & 7) << 4)));
      }
#pragma unroll
      for (int m = 0; m < 4; ++m)
#pragma unroll
        for (int n = 0; n < 4; ++n)
          acc[m][n] = __builtin_amdgcn_mfma_f32_16x16x32_bf16(a[m], bc[n * 2 + ks],
                                                              acc[m][n], 0, 0, 0);
    }
    __builtin_amdgcn_s_setprio(0);
  };

  auto step_body = [&](int s, const short8* bc, short8* bn) {
    asm volatile("s_waitcnt vmcnt(16)" ::: "memory");
    __builtin_amdgcn_sched_barrier(0);
    __builtin_amdgcn_s_barrier();
    __builtin_amdgcn_sched_barrier(0);
    loadB(s + 1, bn);
    issueA(s + 3, (s + 3) & 3);
    compute(s & 3, bc);
  };

  // prologue: A0,A1,B0,A2 so vmcnt(16) uniformly retires through B(s)
  issueA(0, 0);
  issueA(1, 1);
  loadB(0, b0);
  issueA(2, 2);
  for (int s = 0; s < NSTEP; s += 2) {
    step_body(s, b0, b1);
    step_body(s + 1, b1, b0);
  }

  // epilogue: out write + per-block channel sum/sumsq
  float sv[4], qv[4];
#pragma unroll
  for (int n = 0; n < 4; ++n) {
    float s = 0.f, q = 0.f;
    int col = wc * 64 + n * 16 + lr;
#pragma unroll
    for (int m = 0; m < 4; ++m) {
      int rb = row0 + wr * 64 + m * 16 + lg * 4;
#pragma unroll
      for (int e = 0; e < 4; ++e) {
        float x = acc[m][n][e];
        if (rb + e < N_VOX) out[(size_t)(rb + e) * CO + col] = x;
        s += x; q += x * x;
      }
    }
    s += __shfl_xor(s, 16, 64); s += __shfl_xor(s, 32, 64);
    q += __shfl_xor(q, 16, 64); q += __shfl_xor(q, 32, 64);
    sv[n] = s; qv[n] = q;
  }
  __syncthreads();
  if (lg == 0) {
#pragma unroll
    for (int n = 0; n < 4; ++n) {
      int col = wc * 64 + n * 16 + lr;
      sq[wr * 256 + col] = sv[n];
      sq[wr * 256 + 128 + col] = qv[n];
    }
  }
  __syncthreads();
  partial[(size_t)bid * 256 + tid] = sq[tid] + sq[256 + tid];
}

// ---- fallback conv (fp32 gather via VGPR + writeA; B in regs from Wt2) ----
__global__ __launch_bounds__(256, 2) void conv_fb_kernel(
    const float* __restrict__ feat, const u16* __restrict__ Wt2,
    const int* __restrict__ nb, float* __restrict__ out,
    float* __restrict__ partial) {
  __shared__ __align__(16) char smem[46592];
  u16* const Ab = (u16*)smem;               // 2 x 16KB
  int* const nbs = (int*)(smem + 32768);    // 13824B
  float* const sq = (float*)smem;

  const int tid = threadIdx.x;
  const int bid = blockIdx.x;
  const int row0 = bid * BM;

  for (int i = tid; i < BM * KK; i += 256) {
    int gi = row0 * KK + i;
    nbs[i] = (gi < N_VOX * KK) ? nb[gi] : -1;
  }
  __syncthreads();

  const int lane = tid & 63;
  const int wv = tid >> 6;
  const int wr = wv >> 1, wc = wv & 1;
  const int lr = lane & 15, lg = lane >> 4;
  const int arow = tid >> 1;
  const int acol = (tid & 1) * 32;

  f32x4 acc[4][4];
#pragma unroll
  for (int m = 0; m < 4; ++m)
#pragma unroll
    for (int n = 0; n < 4; ++n) acc[m][n] = (f32x4){0.f, 0.f, 0.f, 0.f};

  float4 af[8];
  short8 b0[8], b1[8];

  auto issueAf = [&](int s) {
    int k = s >> 1, half = (s & 1) * 64;
    int src = nbs[arow * KK + k];
    if (src >= 0) {
      const float4* p = (const float4*)(feat + (size_t)src * CI + half + acol);
#pragma unroll
      for (int j = 0; j < 8; ++j) af[j] = p[j];
    } else {
#pragma unroll
      for (int j = 0; j < 8; ++j) af[j] = (float4){0.f, 0.f, 0.f, 0.f};
    }
  };
  auto loadB = [&](int s, short8* bn) {
    int k = s >> 1, half = s & 1;
    const u16* base = Wt2 + (((k * 2 + half) * 16 + wc * 4) * 512) + lane * 8;
#pragma unroll
    for (int n = 0; n < 4; ++n)
#pragma unroll
      for (int ks = 0; ks < 2; ++ks)
        bn[n * 2 + ks] = *(const short8*)(base + (ks * 8 + n) * 512);
  };
  auto writeA = [&](u16* Adst) {
    int v = arow & 7;
#pragma unroll
    for (int q = 0; q < 4; ++q) {
      u16 t8[8];
#pragma unroll
      for (int i = 0; i < 2; ++i) {
        float4 f = af[q * 2 + i];
        t8[i * 4 + 0] = cvt_bf(f.x); t8[i * 4 + 1] = cvt_bf(f.y);
        t8[i * 4 + 2] = cvt_bf(f.z); t8[i * 4 + 3] = cvt_bf(f.w);
      }
      int c_o = (tid & 1) * 4 + q;
      *(uint4*)&Adst[arow * 64 + ((c_o ^ v) << 3)] = *(const uint4*)t8;
    }
  };
  auto compute = [&](const u16* A, const short8* bc) {
#pragma unroll
    for (int ks = 0; ks < 2; ++ks) {
      short8 a[4];
#pragma unroll
      for (int m = 0; m < 4; ++m) {
        int r = wr * 64 + m * 16 + lr;
        a[m] = *(const short8*)((const char*)A + r * 128 +
                                ((ks * 64 + lg * 16) ^ ((r & 7) << 4)));
      }
#pragma unroll
      for (int m = 0; m < 4; ++m)
#pragma unroll
        for (int n = 0; n < 4; ++n)
          acc[m][n] = __builtin_amdgcn_mfma_f32_16x16x32_bf16(a[m], bc[n * 2 + ks],
                                                              acc[m][n], 0, 0, 0);
    }
  };

  issueAf(0);
  loadB(0, b0);
  for (int s = 0; s + 2 <= NSTEP - 1; s += 2) {
    writeA(Ab + (s & 1) * 8192); __syncthreads();
    issueAf(s + 1); loadB(s + 1, b1);
    compute(Ab + (s & 1) * 8192, b0);
    writeA(Ab + ((s + 1) & 1) * 8192); __syncthreads();
    issueAf(s + 2); loadB(s + 2, b0);
    compute(Ab + ((s + 1) & 1) * 8192, b1);
  }
  // s = 52 state: af holds step 52, b0 holds B(52)
  writeA(Ab); __syncthreads();
  issueAf(NSTEP - 1); loadB(NSTEP - 1, b1);
  compute(Ab, b0);
  writeA(Ab + 8192); __syncthreads();
  compute(Ab + 8192, b1);

  float sv[4], qv[4];
#pragma unroll
  for (int n = 0; n < 4; ++n) {
    float s = 0.f, q = 0.f;
    int col = wc * 64 + n * 16 + lr;
#pragma unroll
    for (int m = 0; m < 4; ++m) {
      int rb = row0 + wr * 64 + m * 16 + lg * 4;
#pragma unroll
      for (int e = 0; e < 4; ++e) {
        float x = acc[m][n][e];
        if (rb + e < N_VOX) out[(size_t)(rb + e) * CO + col] = x;
        s += x; q += x * x;
      }
    }
    s += __shfl_xor(s, 16, 64); s += __shfl_xor(s, 32, 64);
    q += __shfl_xor(q, 16, 64); q += __shfl_xor(q, 32, 64);
    sv[n] = s; qv[n] = q;
  }
  __syncthreads();
  if (lg == 0) {
#pragma unroll
    for (int n = 0; n < 4; ++n) {
      int col = wc * 64 + n * 16 + lr;
      sq[wr * 256 + col] = sv[n];
      sq[wr * 256 + 128 + col] = qv[n];
    }
  }
  __syncthreads();
  partial[(size_t)bid * 256 + tid] = sq[tid] + sq[256 + tid];
}

// ---- deterministic 2-stage channel reduction ----
__global__ __launch_bounds__(256) void reduce1_kernel(const float* __restrict__ partial,
                                                      float* __restrict__ partial2) {
  int t = threadIdx.x, b = blockIdx.x;
  float acc = 0.f;
  int jend = (b + 1) * 16; if (jend > NBLK) jend = NBLK;
  for (int j = b * 16; j < jend; ++j) acc += partial[(size_t)j * 256 + t];
  partial2[(size_t)b * 256 + t] = acc;
}

__global__ __launch_bounds__(256) void reduce2_kernel(const float* __restrict__ partial2,
                                                      const float* __restrict__ gamma,
                                                      const float* __restrict__ beta,
                                                      float* __restrict__ stats) {
  __shared__ float sums[256];
  int t = threadIdx.x;
  float acc = 0.f;
  for (int j = 0; j < 98; ++j) acc += partial2[(size_t)j * 256 + t];
  sums[t] = acc;
  __syncthreads();
  if (t < 128) {
    float mean = sums[t] / (float)N_VOX;
    float var = sums[128 + t] / (float)N_VOX - mean * mean;
    float scale = gamma[t] * rsqrtf(var + BN_EPS);
    stats[t] = scale;
    stats[128 + t] = beta[t] - mean * scale;
  }
}

// ---- BN apply + LeakyReLU, in place on d_out ----
__global__ __launch_bounds__(256) void bnact_kernel(float* __restrict__ out,
                                                    const float* __restrict__ stats) {
  __shared__ float s_scale[128], s_shift[128];
  int t = threadIdx.x;
  if (t < 128) { s_scale[t] = stats[t]; s_shift[t] = stats[128 + t]; }
  __syncthreads();
  size_t i = (size_t)blockIdx.x * 256 + t;
  float4* o4 = (float4*)out;
  float4 v = o4[i];
  int c0 = ((int)(i & 31)) << 2;
  float x;
  x = v.x * s_scale[c0 + 0] + s_shift[c0 + 0]; v.x = x > 0.f ? x : LEAK * x;
  x = v.y * s_scale[c0 + 1] + s_shift[c0 + 1]; v.y = x > 0.f ? x : LEAK * x;
  x = v.z * s_scale[c0 + 2] + s_shift[c0 + 2]; v.z = x > 0.f ? x : LEAK * x;
  x = v.w * s_scale[c0 + 3] + s_shift[c0 + 3]; v.w = x > 0.f ? x : LEAK * x;
  o4[i] = v;
}

extern "C" void kernel_launch(void* const* d_in, const int* in_sizes, int n_in,
                              void* d_out, int out_size, void* d_ws, size_t ws_size,
                              hipStream_t stream) {
  const float* feat  = (const float*)d_in[0];
  const float* W     = (const float*)d_in[1];
  // d_in[2] = bias: cancels exactly under training-mode batch norm -> skipped
  const float* gamma = (const float*)d_in[3];
  const float* beta  = (const float*)d_in[4];
  const int*   nb    = (const int*)d_in[5];
  float* out = (float*)d_out;

  char* ws = (char*)d_ws;
  u16*   Wt2      = (u16*)ws;                        // 884,736 B
  float* partial  = (float*)(ws + 884736);           // 1,600,512 B
  float* partial2 = (float*)(ws + 2485248);          // 100,352 B
  float* stats    = (float*)(ws + 2585600);          // 1,024 B
  u16*   zp       = (u16*)(ws + 2586624);            // 256 B zeros
  u16*   featb    = (u16*)(ws + 2586880);            // 51,200,000 B
  const size_t need_fast = 2586880u + 51200000u;

  hipLaunchKernelGGL(wcast2_kernel, dim3(216), dim3(256), 0, stream, W, Wt2);
  if (ws_size >= need_fast) {
    hipMemsetAsync(zp, 0, 256, stream);
    hipLaunchKernelGGL(fcast_kernel, dim3(12500), dim3(256), 0, stream, feat, featb);
    hipLaunchKernelGGL(conv_kernel, dim3(NBLK), dim3(256), 0, stream,
                       featb, Wt2, nb, zp, out, partial);
  } else {
    hipLaunchKernelGGL(conv_fb_kernel, dim3(NBLK), dim3(256), 0, stream,
                       feat, Wt2, nb, out, partial);
  }
  hipLaunchKernelGGL(reduce1_kernel, dim3(98), dim3(256), 0, stream, partial, partial2);
  hipLaunchKernelGGL(reduce2_kernel, dim3(1), dim3(256), 0, stream, partial2, gamma, beta, stats);
  hipLaunchKernelGGL(bnact_kernel, dim3(25000), dim3(256), 0, stream, out, stats);
}